// Round 2
// baseline (1112.509 us; speedup 1.0000x reference)
//
#include <hip/hip_runtime.h>
#include <hip/hip_bf16.h>

// MoE top-2-of-8 FFN + shared expert + router losses, MI355X gfx950.
// R5: router/scatter atomic de-serialization (274us -> noise).
// R6: all four GEMMs ported to the 256x256-tile / BK=64 / 8-wave / 8-phase
//     counted-vmcnt template (HK-derived m201 structure):
//       - per phase: {ds_read reg subtile | stage 1 half-tile} -> s_barrier ->
//         lgkmcnt(0) -> setprio(1) 16x MFMA setprio(0) -> s_barrier
//       - stage schedule (tile T, slot s=T&1):
//           ph1: (T+1).A-half0 -> slot s^1   (old A0 last read at (T-1).ph3)
//           ph2: (T+1).A-half1 -> slot s^1
//           ph3: (T+2).B-half0 -> slot s     (B0(s) last read at T.ph2)
//           ph4: (T+2).B-half1 -> slot s, then s_waitcnt vmcnt(4)
//         vmcnt(4) leaves only the 2 newest half-tiles (4 loads) in flight =>
//         tile T+1 fully landed before its ph1 reads. Tail: vmcnt(0).
//     Halves staging traffic per output elem vs 128^2 (expert_values LDS-level
//     2.23 GB -> 1.09 GB) and stops draining vmcnt to 0 every K-step.
//     Grouped segments padded to 256 (PERM_CAP 18432, MAX_TILES 72).

#define N_TOK 8192
#define DM    1024
#define HD    4096
#define NE    8
#define NKTOT 16384            // N_TOK * 2
#define PERM_CAP 18432         // NKTOT + NE*256 (segment padding to 256)
#define MAX_TILES 72           // sum ceil(T_e/256) <= NKTOT/256 + NE
#define RTOK_BLK 16            // router tokens per block

typedef __attribute__((ext_vector_type(8))) short bhalf8;
typedef __attribute__((ext_vector_type(4))) float floatx4;

#define MEMBAR asm volatile("" ::: "memory")
#define SBAR   do { MEMBAR; __builtin_amdgcn_s_barrier(); MEMBAR; } while (0)

__device__ __forceinline__ unsigned short f2bf(float f) {
  union { float f; unsigned int u; } v; v.f = f;
  unsigned int u = v.u;
  return (unsigned short)((u + 0x7fffu + ((u >> 16) & 1u)) >> 16);  // RNE
}

__device__ __forceinline__ float bf2f(unsigned short h) {
  union { unsigned int u; float f; } v; v.u = ((unsigned int)h) << 16;
  return v.f;
}

__device__ __forceinline__ float gelu_tanh(float h) {
  // jax.nn.gelu default (approximate=True)
  float u = 0.7978845608028654f * (h + 0.044715f * h * h * h);
  float t = 1.0f - 2.0f / (1.0f + __expf(2.0f * u));   // tanh(u)
  return 0.5f * h * (1.0f + t);
}

// global -> LDS direct DMA, 16B/lane. LDS dest is wave-uniform base + lane*16.
__device__ __forceinline__ void gload16(const unsigned short* g, void* l) {
  __builtin_amdgcn_global_load_lds(
      (const __attribute__((address_space(1))) void*)g,
      (__attribute__((address_space(3))) void*)l, 16, 0, 0);
}

// ---------------- init (ws is poisoned 0xAA each call) ----------------
__global__ void init_kernel(int* perm, float* permw, float* usage, float* zsum,
                            int* counts, int* fill) {
  int i = blockIdx.x * 256 + threadIdx.x;
  if (i < PERM_CAP) { perm[i] = 0; permw[i] = 0.0f; }
  if (i < NE) { usage[i] = 0.0f; counts[i] = 0; fill[i] = 0; }
  if (i == 0) zsum[0] = 0.0f;
}

// ---------------- x fp32 -> bf16 ----------------
__global__ void cvt_x_kernel(const float* __restrict__ x, unsigned short* __restrict__ xb) {
  size_t i = (size_t)(blockIdx.x * 256 + threadIdx.x) * 4;
  float4 v = *(const float4*)(x + i);
  ushort4 o;
  o.x = f2bf(v.x); o.y = f2bf(v.y); o.z = f2bf(v.z); o.w = f2bf(v.w);
  *(ushort4*)(xb + i) = o;
}

// ---------------- router: logits, top-2 softmax, aux-loss partials ----------------
__global__ void router_kernel(const float* __restrict__ x, const float* __restrict__ gw,
                              int* __restrict__ idxb, float* __restrict__ wbuf,
                              float* __restrict__ usage, float* __restrict__ zsum,
                              int* __restrict__ counts) {
  __shared__ float s_use[NE];
  __shared__ int   s_cnt[NE];
  __shared__ float s_z;
  int t = threadIdx.x;
  if (t < NE) { s_use[t] = 0.0f; s_cnt[t] = 0; }
  if (t == 0) s_z = 0.0f;
  __syncthreads();

  int wave = t >> 6;
  int lane = t & 63;

  float luse[NE]; int lcnt[NE];
#pragma unroll
  for (int e = 0; e < NE; e++) { luse[e] = 0.0f; lcnt[e] = 0; }
  float lz = 0.0f;

#pragma unroll
  for (int i = 0; i < 4; i++) {
    int n = blockIdx.x * RTOK_BLK + wave * 4 + i;
    const float* xr = x + (size_t)n * DM;
    float acc[NE];
#pragma unroll
    for (int e = 0; e < NE; e++) acc[e] = 0.0f;
    for (int d = lane; d < DM; d += 64) {
      float xv = xr[d];
      const float* g = gw + (size_t)d * NE;
#pragma unroll
      for (int e = 0; e < NE; e++) acc[e] += xv * g[e];
    }
#pragma unroll
    for (int e = 0; e < NE; e++) {
#pragma unroll
      for (int off = 32; off > 0; off >>= 1) acc[e] += __shfl_xor(acc[e], off);
    }
    if (lane == 0) {
      float m1 = acc[0]; int i1 = 0;
#pragma unroll
      for (int e = 1; e < NE; e++) if (acc[e] > m1) { m1 = acc[e]; i1 = e; }
      float m2 = -3.0e38f; int i2 = 0;
#pragma unroll
      for (int e = 0; e < NE; e++) if (e != i1 && acc[e] > m2) { m2 = acc[e]; i2 = e; }
      float e1 = __expf(m2 - m1);
      float w1 = 1.0f / (1.0f + e1);
      float w2 = e1 / (1.0f + e1);
      float s = 0.0f;
#pragma unroll
      for (int e = 0; e < NE; e++) s += __expf(acc[e] - m1);
      float lse = m1 + __logf(s);
      idxb[n * 2 + 0] = i1; idxb[n * 2 + 1] = i2;
      wbuf[n * 2 + 0] = w1; wbuf[n * 2 + 1] = w2;
      luse[i1] += w1; luse[i2] += w2;
      lcnt[i1]++;     lcnt[i2]++;
      lz += lse * lse;
    }
  }

  if (lane == 0) {
#pragma unroll
    for (int e = 0; e < NE; e++) {
      atomicAdd(&s_use[e], luse[e]);
      atomicAdd(&s_cnt[e], lcnt[e]);
    }
    atomicAdd(&s_z, lz);
  }
  __syncthreads();
  if (t < NE) {
    atomicAdd(&usage[t], s_use[t]);
    atomicAdd(&counts[t], s_cnt[t]);
  }
  if (t == 0) atomicAdd(zsum, s_z);
}

// ---------------- scan: padded segment offsets, tile table, router loss ----------------
__global__ void scan_kernel(const int* __restrict__ counts, int* __restrict__ poff,
                            int* __restrict__ tileE, int* __restrict__ tileR,
                            int* __restrict__ nTiles,
                            const float* __restrict__ usage, const float* __restrict__ zsum,
                            float* __restrict__ lossOut) {
  if (threadIdx.x == 0 && blockIdx.x == 0) {
    int run = 0, nt = 0;
    for (int e = 0; e < NE; e++) {
      poff[e] = run;
      int t = (counts[e] + 255) >> 8;
      for (int i = 0; i < t; i++) { tileE[nt] = e; tileR[nt] = run + i * 256; nt++; }
      run += t << 8;
    }
    *nTiles = nt;
    float mean = 0.0f;
    for (int e = 0; e < NE; e++) mean += usage[e];
    mean *= (1.0f / NE);
    float var = 0.0f;
    for (int e = 0; e < NE; e++) { float d = usage[e] - mean; var += d * d; }
    var *= (1.0f / NE);
    float bal = sqrtf(var) / mean * 0.01f;
    float z = (zsum[0] / (float)N_TOK) * 0.001f;
    lossOut[0] = bal + z;
  }
}

// ---------------- scatter tokens into per-expert segments ----------------
__global__ void scatter_kernel(const int* __restrict__ idxb, const float* __restrict__ wbuf,
                               const int* __restrict__ poff, int* __restrict__ fill,
                               int* __restrict__ perm, float* __restrict__ permw,
                               int* __restrict__ pos) {
  __shared__ int lcnt[NE];
  __shared__ int lbase[NE];
  int t = threadIdx.x;
  if (t < NE) lcnt[t] = 0;
  __syncthreads();
  int i = blockIdx.x * 256 + t;          // grid sized exactly: i < NKTOT
  int e = idxb[i];
  int r = atomicAdd(&lcnt[e], 1);        // LDS rank within block
  __syncthreads();
  if (t < NE) lbase[t] = atomicAdd(&fill[t], lcnt[t]);
  __syncthreads();
  int p = poff[e] + lbase[e] + r;
  perm[p] = i >> 1;
  permw[p] = wbuf[i];
  pos[i] = p;
}

// ---------------- transpose+convert: src fp32 [R][C] -> dst bf16 [C][R], batched ----------------
__global__ void transpose_cvt_kernel(const float* __restrict__ src,
                                     unsigned short* __restrict__ dst, int R, int C) {
  __shared__ float tile[64][65];
  size_t bo = (size_t)blockIdx.z * R * C;
  src += bo; dst += bo;
  int r0 = blockIdx.x * 64, c0 = blockIdx.y * 64;
  int c = threadIdx.x & 63, r = threadIdx.x >> 6;
#pragma unroll
  for (int i = 0; i < 16; i++)
    tile[r + i * 4][c] = src[(size_t)(r0 + r + i * 4) * C + c0 + c];
  __syncthreads();
#pragma unroll
  for (int i = 0; i < 16; i++) {
    int oc = r + i * 4;           // src col -> dst row offset
    float v = tile[c][oc];        // = src[r0+c][c0+oc]
    dst[(size_t)(c0 + oc) * R + r0 + c] = f2bf(v);
  }
}

// ---------------- combine: out[t] += eout[pos0[t]] + eout[pos1[t]] ----------------
__global__ void combine_kernel(float* __restrict__ out,
                               const unsigned short* __restrict__ eout,
                               const int* __restrict__ pos) {
  int t = blockIdx.x;
  int d = threadIdx.x * 8;
  int p0 = pos[t * 2], p1 = pos[t * 2 + 1];
  float* o = out + (size_t)t * DM + d;
  const unsigned short* e0 = eout + (size_t)p0 * DM + d;
  const unsigned short* e1 = eout + (size_t)p1 * DM + d;
  float4 a = *(const float4*)(o);
  float4 b = *(const float4*)(o + 4);
  ushort4 u0a = *(const ushort4*)(e0), u0b = *(const ushort4*)(e0 + 4);
  ushort4 u1a = *(const ushort4*)(e1), u1b = *(const ushort4*)(e1 + 4);
  a.x += bf2f(u0a.x) + bf2f(u1a.x);
  a.y += bf2f(u0a.y) + bf2f(u1a.y);
  a.z += bf2f(u0a.z) + bf2f(u1a.z);
  a.w += bf2f(u0a.w) + bf2f(u1a.w);
  b.x += bf2f(u0b.x) + bf2f(u1b.x);
  b.y += bf2f(u0b.y) + bf2f(u1b.y);
  b.z += bf2f(u0b.z) + bf2f(u1b.z);
  b.w += bf2f(u0b.w) + bf2f(u1b.w);
  *(float4*)(o) = a;
  *(float4*)(o + 4) = b;
}

// ---------------- 256x256xBK64 bf16 MFMA GEMM, 8-wave 8-phase counted-vmcnt ----------------
// 512 threads = 8 waves (2 M-rows x 4 N-cols of 128x64 wave tiles).
// LDS: A[2][256][64] + B[2][256][64] bf16 = 128 KB (1 block/CU).
// Staging: pre-swizzled global source (chunk cc = (t&7)^(rsub&7)) + linear
// global_load_lds dest; read side XORs the 16B-chunk with row&7 (bank-conflict
// free, same scheme as the verified 128^2 version).
template<int MODE>
__device__ __forceinline__ void gemm_body(
    const unsigned short* __restrict__ A,
    const unsigned short* __restrict__ BT,
    const float* __restrict__ bias,
    float* __restrict__ outF,
    unsigned short* __restrict__ outH,
    int Kd, int Nd,
    const int* __restrict__ perm,
    const float* __restrict__ permw,
    const int* __restrict__ tileE,
    const int* __restrict__ tileR,
    const int* __restrict__ nTiles) {
  __shared__ __align__(16) unsigned short As[2][16384];   // [slot][256*64]
  __shared__ __align__(16) unsigned short Bs[2][16384];

  int id = blockIdx.x;
  int xcd = id & 7, q = id >> 3;
  int mt, ntile;
  if (MODE == 0)      { mt = xcd * 4 + (q & 3); ntile = q >> 2; }   // 512 blk: 32m x 16n
  else if (MODE == 1) { mt = xcd * 4 + (q & 3); ntile = q >> 2; }   // 128 blk: 32m x 4n
  else if (MODE == 2) { mt = xcd * 9 + (q >> 4); ntile = q & 15; }  // 1152 blk: 72m x 16n
  else                { mt = xcd * 9 + (q >> 2); ntile = q & 3; }   // 288 blk: 72m x 4n

  int n0 = ntile * 256;
  int prow0 = 0, m0 = 0;
  if (MODE >= 2) {
    if (mt >= *nTiles) return;
    int e = tileE[mt];
    prow0 = tileR[mt];
    BT += (size_t)e * Kd * Nd;
    bias += (size_t)e * Nd;
  } else {
    m0 = mt * 256;
  }

  int t = threadIdx.x;
  int wid = t >> 6, lane = t & 63;
  int rsub = t >> 3;                // 0..63: row within a 64-row staging call
  int cc = (t & 7) ^ (rsub & 7);    // swizzled global 16B-chunk index
  const unsigned short* aptr[4];
  const unsigned short* bptr[4];
#pragma unroll
  for (int c = 0; c < 4; c++) {     // c = half*2 + sub; row r = c*64 + rsub
    int r = c * 64 + rsub;
    size_t grow;
    if (MODE == 2)      grow = (size_t)perm[prow0 + r];
    else if (MODE == 3) grow = (size_t)(prow0 + r);
    else                grow = (size_t)(m0 + r);
    aptr[c] = A + grow * Kd + cc * 8;
    bptr[c] = BT + (size_t)(n0 + r) * Kd + cc * 8;
  }
  // wave-uniform LDS staging bases (HW adds lane*16)
  char* aS = (char*)&As[0][0] + wid * 1024;
  char* bS = (char*)&Bs[0][0] + wid * 1024;

#define STAGE_A(kt, h, slot) do { \
    gload16(aptr[(h)*2]     + (kt)*64, aS + (slot)*32768 + (h)*16384); \
    gload16(aptr[(h)*2 + 1] + (kt)*64, aS + (slot)*32768 + (h)*16384 + 8192); } while (0)
#define STAGE_B(kt, h, slot) do { \
    gload16(bptr[(h)*2]     + (kt)*64, bS + (slot)*32768 + (h)*16384); \
    gload16(bptr[(h)*2 + 1] + (kt)*64, bS + (slot)*32768 + (h)*16384 + 8192); } while (0)

  int wr = wid >> 2, wc = wid & 3;          // wave tile: rows wr*128, cols wc*64
  int lr = lane & 15, lq = lane >> 4;
  int rx = lr & 7;
  int aoff = (wr * 128 + lr) * 64;          // element offsets within a slot
  int boff = (wc * 64 + lr) * 64;
  int c0 = (lq ^ rx) * 8;                   // kk=0 chunk; kk=1 is c0^32

  floatx4 acc[8][4];
#pragma unroll
  for (int i = 0; i < 8; i++)
#pragma unroll
    for (int j = 0; j < 4; j++) acc[i][j] = (floatx4){0.f, 0.f, 0.f, 0.f};

  int nkt = Kd >> 6;

  // prologue: tile0 all 4 halves + tile1 B-halves; wait tile0 landed.
  STAGE_A(0, 0, 0); STAGE_A(0, 1, 0);
  STAGE_B(0, 0, 0); STAGE_B(0, 1, 0);
  STAGE_B(1, 0, 1); STAGE_B(1, 1, 1);
  asm volatile("s_waitcnt vmcnt(4)" ::: "memory");
  SBAR;

  bhalf8 a[4][2], bL[2][2], bH[2][2];
  for (int kt = 0; kt < nkt; ++kt) {
    int s = kt & 1;
    const unsigned short* Ax = &As[0][0] + s * 16384;
    const unsigned short* Bx = &Bs[0][0] + s * 16384;

    // ---- phase 1: read A m-lo (8) + B n-lo (4); stage (kt+1).A0 ----
#pragma unroll
    for (int i = 0; i < 4; i++) {
      a[i][0] = *(const bhalf8*)&Ax[aoff + i * 1024 + c0];
      a[i][1] = *(const bhalf8*)&Ax[aoff + i * 1024 + (c0 ^ 32)];
    }
#pragma unroll
    for (int j = 0; j < 2; j++) {
      bL[j][0] = *(const bhalf8*)&Bx[boff + j * 1024 + c0];
      bL[j][1] = *(const bhalf8*)&Bx[boff + j * 1024 + (c0 ^ 32)];
    }
    if (kt + 1 < nkt) STAGE_A(kt + 1, 0, s ^ 1);
    SBAR;
    asm volatile("s_waitcnt lgkmcnt(0)" ::: "memory");
    __builtin_amdgcn_s_setprio(1);
#pragma unroll
    for (int kk = 0; kk < 2; kk++)
#pragma unroll
      for (int i = 0; i < 4; i++)
#pragma unroll
        for (int j = 0; j < 2; j++)
          acc[i][j] = __builtin_amdgcn_mfma_f32_16x16x32_bf16(a[i][kk], bL[j][kk], acc[i][j], 0, 0, 0);
    __builtin_amdgcn_s_setprio(0);
    SBAR;

    // ---- phase 2: read B n-hi (4); stage (kt+1).A1 ----
#pragma unroll
    for (int j = 0; j < 2; j++) {
      bH[j][0] = *(const bhalf8*)&Bx[boff + (j + 2) * 1024 + c0];
      bH[j][1] = *(const bhalf8*)&Bx[boff + (j + 2) * 1024 + (c0 ^ 32)];
    }
    if (kt + 1 < nkt) STAGE_A(kt + 1, 1, s ^ 1);
    SBAR;
    asm volatile("s_waitcnt lgkmcnt(0)" ::: "memory");
    __builtin_amdgcn_s_setprio(1);
#pragma unroll
    for (int kk = 0; kk < 2; kk++)
#pragma unroll
      for (int i = 0; i < 4; i++)
#pragma unroll
        for (int j = 0; j < 2; j++)
          acc[i][j + 2] = __builtin_amdgcn_mfma_f32_16x16x32_bf16(a[i][kk], bH[j][kk], acc[i][j + 2], 0, 0, 0);
    __builtin_amdgcn_s_setprio(0);
    SBAR;

    // ---- phase 3: read A m-hi (8, reuse regs); stage (kt+2).B0 into slot s ----
#pragma unroll
    for (int i = 0; i < 4; i++) {
      a[i][0] = *(const bhalf8*)&Ax[aoff + (i + 4) * 1024 + c0];
      a[i][1] = *(const bhalf8*)&Ax[aoff + (i + 4) * 1024 + (c0 ^ 32)];
    }
    if (kt + 2 < nkt) STAGE_B(kt + 2, 0, s);
    SBAR;
    asm volatile("s_waitcnt lgkmcnt(0)" ::: "memory");
    __builtin_amdgcn_s_setprio(1);
#pragma unroll
    for (int kk = 0; kk < 2; kk++)
#pragma unroll
      for (int i = 0; i < 4; i++)
#pragma unroll
        for (int j = 0; j < 2; j++)
          acc[i + 4][j] = __builtin_amdgcn_mfma_f32_16x16x32_bf16(a[i][kk], bL[j][kk], acc[i + 4][j], 0, 0, 0);
    __builtin_amdgcn_s_setprio(0);
    SBAR;

    // ---- phase 4: no reads; stage (kt+2).B1; counted vmcnt ----
    if (kt + 2 < nkt) {
      STAGE_B(kt + 2, 1, s);
      asm volatile("s_waitcnt vmcnt(4)" ::: "memory");   // leave only (kt+2).B0/B1
    } else {
      asm volatile("s_waitcnt vmcnt(0)" ::: "memory");   // tail: drain all
    }
    SBAR;
    __builtin_amdgcn_s_setprio(1);
#pragma unroll
    for (int kk = 0; kk < 2; kk++)
#pragma unroll
      for (int i = 0; i < 4; i++)
#pragma unroll
        for (int j = 0; j < 2; j++)
          acc[i + 4][j + 2] = __builtin_amdgcn_mfma_f32_16x16x32_bf16(a[i][kk], bH[j][kk], acc[i + 4][j + 2], 0, 0, 0);
    __builtin_amdgcn_s_setprio(0);
    SBAR;
  }
#undef STAGE_A
#undef STAGE_B

  // epilogue: frag D[row=lq*4+r][col=lr]
#pragma unroll
  for (int jj = 0; jj < 4; jj++) {
    int ncol = n0 + wc * 64 + jj * 16 + lr;
    float bb = bias[ncol];
#pragma unroll
    for (int i = 0; i < 8; i++) {
#pragma unroll
      for (int r = 0; r < 4; r++) {
        int mrow = wr * 128 + i * 16 + lq * 4 + r;      // local row 0..255
        float v = acc[i][jj][r] + bb;
        if (MODE == 0) {
          outH[(size_t)(m0 + mrow) * Nd + ncol] = f2bf(gelu_tanh(v));
        } else if (MODE == 1) {
          outF[(size_t)(m0 + mrow) * Nd + ncol] = v;
        } else if (MODE == 2) {
          outH[(size_t)(prow0 + mrow) * Nd + ncol] = f2bf(gelu_tanh(v));
        } else {
          int prow = prow0 + mrow;
          float w = permw[prow];
          outH[(size_t)prow * Nd + ncol] = f2bf(w * v);   // weighted expert out
        }
      }
    }
  }
}

// distinct names per mode so rocprof shows the per-GEMM breakdown
__global__ __launch_bounds__(512, 2) void gemm_shared_keys(
    const unsigned short* A, const unsigned short* BT, const float* bias,
    float* outF, unsigned short* outH, int Kd, int Nd,
    const int* perm, const float* permw, const int* tE, const int* tR, const int* nT) {
  gemm_body<0>(A, BT, bias, outF, outH, Kd, Nd, perm, permw, tE, tR, nT);
}
__global__ __launch_bounds__(512, 2) void gemm_shared_values(
    const unsigned short* A, const unsigned short* BT, const float* bias,
    float* outF, unsigned short* outH, int Kd, int Nd,
    const int* perm, const float* permw, const int* tE, const int* tR, const int* nT) {
  gemm_body<1>(A, BT, bias, outF, outH, Kd, Nd, perm, permw, tE, tR, nT);
}
__global__ __launch_bounds__(512, 2) void gemm_expert_keys(
    const unsigned short* A, const unsigned short* BT, const float* bias,
    float* outF, unsigned short* outH, int Kd, int Nd,
    const int* perm, const float* permw, const int* tE, const int* tR, const int* nT) {
  gemm_body<2>(A, BT, bias, outF, outH, Kd, Nd, perm, permw, tE, tR, nT);
}
__global__ __launch_bounds__(512, 2) void gemm_expert_values(
    const unsigned short* A, const unsigned short* BT, const float* bias,
    float* outF, unsigned short* outH, int Kd, int Nd,
    const int* perm, const float* permw, const int* tE, const int* tR, const int* nT) {
  gemm_body<3>(A, BT, bias, outF, outH, Kd, Nd, perm, permw, tE, tR, nT);
}

extern "C" void kernel_launch(void* const* d_in, const int* in_sizes, int n_in,
                              void* d_out, int out_size, void* d_ws, size_t ws_size,
                              hipStream_t stream) {
  const float* x        = (const float*)d_in[0];
  const float* gate_w   = (const float*)d_in[1];
  const float* keys_w   = (const float*)d_in[2];
  const float* keys_b   = (const float*)d_in[3];
  const float* values_w = (const float*)d_in[4];
  const float* values_b = (const float*)d_in[5];
  const float* sk_w     = (const float*)d_in[6];
  const float* sk_b     = (const float*)d_in[7];
  const float* sv_w     = (const float*)d_in[8];
  const float* sv_b     = (const float*)d_in[9];
  float* out = (float*)d_out;

  char* p = (char*)d_ws;
  unsigned short* xb   = (unsigned short*)p; p += (size_t)N_TOK * DM * 2;     // 16 MB
  unsigned short* wt   = (unsigned short*)p; p += (size_t)NE * DM * HD * 2;   // 64 MB (phased)
  unsigned short* hid  = (unsigned short*)p; p += (size_t)PERM_CAP * HD * 2;  // 151 MB
  unsigned short* eout = (unsigned short*)p; p += (size_t)PERM_CAP * DM * 2;  // 37.8 MB
  int*   idxb   = (int*)p;   p += NKTOT * 4;
  float* wbuf   = (float*)p; p += NKTOT * 4;
  int*   perm   = (int*)p;   p += PERM_CAP * 4;
  float* permw  = (float*)p; p += PERM_CAP * 4;
  int*   pos    = (int*)p;   p += NKTOT * 4;
  int*   counts = (int*)p;   p += NE * 4;
  int*   fill   = (int*)p;   p += NE * 4;
  int*   poff   = (int*)p;   p += NE * 4;
  float* usage  = (float*)p; p += NE * 4;
  float* zsum   = (float*)p; p += 16;
  int*   tileE  = (int*)p;   p += MAX_TILES * 4;
  int*   tileR  = (int*)p;   p += MAX_TILES * 4;
  int*   nTiles = (int*)p;   p += 16;

  float* lossOut = out + (size_t)N_TOK * DM;

  // 1) init + convert + router
  init_kernel<<<(PERM_CAP + 255) / 256, 256, 0, stream>>>(perm, permw, usage, zsum, counts, fill);
  cvt_x_kernel<<<(N_TOK * DM / 4 + 255) / 256, 256, 0, stream>>>(x, xb);
  router_kernel<<<N_TOK / RTOK_BLK, 256, 0, stream>>>(x, gate_w, idxb, wbuf, usage, zsum, counts);
  scan_kernel<<<1, 64, 0, stream>>>(counts, poff, tileE, tileR, nTiles, usage, zsum, lossOut);
  scatter_kernel<<<NKTOT / 256, 256, 0, stream>>>(idxb, wbuf, poff, fill, perm, permw, pos);

  // 2) shared expert: hid = gelu(x @ Wk + b); out = hid @ Wv + b
  transpose_cvt_kernel<<<dim3(DM / 64, HD / 64, 1), 256, 0, stream>>>(sk_w, wt, DM, HD);
  gemm_shared_keys<<<512, 512, 0, stream>>>(                // 8 xcd * 4 m * 16 n
      xb, wt, sk_b, nullptr, hid, DM, HD, perm, permw, tileE, tileR, nTiles);
  transpose_cvt_kernel<<<dim3(HD / 64, DM / 64, 1), 256, 0, stream>>>(sv_w, wt, HD, DM);
  gemm_shared_values<<<128, 512, 0, stream>>>(              // 8 xcd * 4 m * 4 n
      hid, wt, sv_b, out, nullptr, HD, DM, perm, permw, tileE, tileR, nTiles);

  // 3) routed experts (grouped, sparse top-2)
  transpose_cvt_kernel<<<dim3(DM / 64, HD / 64, NE), 256, 0, stream>>>(keys_w, wt, DM, HD);
  gemm_expert_keys<<<1152, 512, 0, stream>>>(               // 8 xcd * 9 m * 16 n
      xb, wt, keys_b, nullptr, hid, DM, HD, perm, permw, tileE, tileR, nTiles);
  transpose_cvt_kernel<<<dim3(HD / 64, DM / 64, NE), 256, 0, stream>>>(values_w, wt, HD, DM);
  gemm_expert_values<<<288, 512, 0, stream>>>(              // 8 xcd * 9 m * 4 n
      hid, wt, values_b, nullptr, eout, HD, DM, perm, permw, tileE, tileR, nTiles);

  // 4) out += top-2 expert contributions
  combine_kernel<<<N_TOK, 128, 0, stream>>>(out, eout, pos);
}

// Round 3
// 1019.218 us; speedup vs baseline: 1.0915x; 1.0915x over previous
//
#include <hip/hip_runtime.h>
#include <hip/hip_bf16.h>

// MoE top-2-of-8 FFN + shared expert + router losses, MI355X gfx950.
// R5: router/scatter atomic de-serialization (274us -> noise).
// R6: 256^2 8-wave 8-phase counted-vmcnt GEMM template (kept for keys GEMMs).
// R7: grid-quantization fix for the N=1024 GEMMs. With 1 block/CU and uniform
//     T_block, time = ceil(G/256)*T: expert_values G=288 -> 2 waves at 56% util;
//     shared_values G=128 -> half machine idle. New BM256xBN128 2-phase body
//     with a 3-slot LDS ring (144 KB): sv -> 256 blocks (exactly 1 wave),
//     ev -> 576 blocks of T/2 (1.5T). Ring stages tile kt+2 during kt
//     (vmcnt(6) = newest tile only in flight) -> ~2 K-tiles of staging lead,
//     covering L3 latency on hid/weight panels. keys GEMMs unchanged as A/B.

#define N_TOK 8192
#define DM    1024
#define HD    4096
#define NE    8
#define NKTOT 16384            // N_TOK * 2
#define PERM_CAP 18432         // NKTOT + NE*256 (segment padding to 256)
#define MAX_TILES 72           // sum ceil(T_e/256) <= NKTOT/256 + NE
#define RTOK_BLK 16            // router tokens per block

typedef __attribute__((ext_vector_type(8))) short bhalf8;
typedef __attribute__((ext_vector_type(4))) float floatx4;

#define MEMBAR asm volatile("" ::: "memory")
#define SBAR   do { MEMBAR; __builtin_amdgcn_s_barrier(); MEMBAR; } while (0)

__device__ __forceinline__ unsigned short f2bf(float f) {
  union { float f; unsigned int u; } v; v.f = f;
  unsigned int u = v.u;
  return (unsigned short)((u + 0x7fffu + ((u >> 16) & 1u)) >> 16);  // RNE
}

__device__ __forceinline__ float bf2f(unsigned short h) {
  union { unsigned int u; float f; } v; v.u = ((unsigned int)h) << 16;
  return v.f;
}

__device__ __forceinline__ float gelu_tanh(float h) {
  // jax.nn.gelu default (approximate=True)
  float u = 0.7978845608028654f * (h + 0.044715f * h * h * h);
  float t = 1.0f - 2.0f / (1.0f + __expf(2.0f * u));   // tanh(u)
  return 0.5f * h * (1.0f + t);
}

// global -> LDS direct DMA, 16B/lane. LDS dest is wave-uniform base + lane*16.
__device__ __forceinline__ void gload16(const unsigned short* g, void* l) {
  __builtin_amdgcn_global_load_lds(
      (const __attribute__((address_space(1))) void*)g,
      (__attribute__((address_space(3))) void*)l, 16, 0, 0);
}

// ---------------- init (ws is poisoned 0xAA each call) ----------------
__global__ void init_kernel(int* perm, float* permw, float* usage, float* zsum,
                            int* counts, int* fill) {
  int i = blockIdx.x * 256 + threadIdx.x;
  if (i < PERM_CAP) { perm[i] = 0; permw[i] = 0.0f; }
  if (i < NE) { usage[i] = 0.0f; counts[i] = 0; fill[i] = 0; }
  if (i == 0) zsum[0] = 0.0f;
}

// ---------------- x fp32 -> bf16 ----------------
__global__ void cvt_x_kernel(const float* __restrict__ x, unsigned short* __restrict__ xb) {
  size_t i = (size_t)(blockIdx.x * 256 + threadIdx.x) * 4;
  float4 v = *(const float4*)(x + i);
  ushort4 o;
  o.x = f2bf(v.x); o.y = f2bf(v.y); o.z = f2bf(v.z); o.w = f2bf(v.w);
  *(ushort4*)(xb + i) = o;
}

// ---------------- router: logits, top-2 softmax, aux-loss partials ----------------
__global__ void router_kernel(const float* __restrict__ x, const float* __restrict__ gw,
                              int* __restrict__ idxb, float* __restrict__ wbuf,
                              float* __restrict__ usage, float* __restrict__ zsum,
                              int* __restrict__ counts) {
  __shared__ float s_use[NE];
  __shared__ int   s_cnt[NE];
  __shared__ float s_z;
  int t = threadIdx.x;
  if (t < NE) { s_use[t] = 0.0f; s_cnt[t] = 0; }
  if (t == 0) s_z = 0.0f;
  __syncthreads();

  int wave = t >> 6;
  int lane = t & 63;

  float luse[NE]; int lcnt[NE];
#pragma unroll
  for (int e = 0; e < NE; e++) { luse[e] = 0.0f; lcnt[e] = 0; }
  float lz = 0.0f;

#pragma unroll
  for (int i = 0; i < 4; i++) {
    int n = blockIdx.x * RTOK_BLK + wave * 4 + i;
    const float* xr = x + (size_t)n * DM;
    float acc[NE];
#pragma unroll
    for (int e = 0; e < NE; e++) acc[e] = 0.0f;
    for (int d = lane; d < DM; d += 64) {
      float xv = xr[d];
      const float* g = gw + (size_t)d * NE;
#pragma unroll
      for (int e = 0; e < NE; e++) acc[e] += xv * g[e];
    }
#pragma unroll
    for (int e = 0; e < NE; e++) {
#pragma unroll
      for (int off = 32; off > 0; off >>= 1) acc[e] += __shfl_xor(acc[e], off);
    }
    if (lane == 0) {
      float m1 = acc[0]; int i1 = 0;
#pragma unroll
      for (int e = 1; e < NE; e++) if (acc[e] > m1) { m1 = acc[e]; i1 = e; }
      float m2 = -3.0e38f; int i2 = 0;
#pragma unroll
      for (int e = 0; e < NE; e++) if (e != i1 && acc[e] > m2) { m2 = acc[e]; i2 = e; }
      float e1 = __expf(m2 - m1);
      float w1 = 1.0f / (1.0f + e1);
      float w2 = e1 / (1.0f + e1);
      float s = 0.0f;
#pragma unroll
      for (int e = 0; e < NE; e++) s += __expf(acc[e] - m1);
      float lse = m1 + __logf(s);
      idxb[n * 2 + 0] = i1; idxb[n * 2 + 1] = i2;
      wbuf[n * 2 + 0] = w1; wbuf[n * 2 + 1] = w2;
      luse[i1] += w1; luse[i2] += w2;
      lcnt[i1]++;     lcnt[i2]++;
      lz += lse * lse;
    }
  }

  if (lane == 0) {
#pragma unroll
    for (int e = 0; e < NE; e++) {
      atomicAdd(&s_use[e], luse[e]);
      atomicAdd(&s_cnt[e], lcnt[e]);
    }
    atomicAdd(&s_z, lz);
  }
  __syncthreads();
  if (t < NE) {
    atomicAdd(&usage[t], s_use[t]);
    atomicAdd(&counts[t], s_cnt[t]);
  }
  if (t == 0) atomicAdd(zsum, s_z);
}

// ---------------- scan: padded segment offsets, tile table, router loss ----------------
__global__ void scan_kernel(const int* __restrict__ counts, int* __restrict__ poff,
                            int* __restrict__ tileE, int* __restrict__ tileR,
                            int* __restrict__ nTiles,
                            const float* __restrict__ usage, const float* __restrict__ zsum,
                            float* __restrict__ lossOut) {
  if (threadIdx.x == 0 && blockIdx.x == 0) {
    int run = 0, nt = 0;
    for (int e = 0; e < NE; e++) {
      poff[e] = run;
      int t = (counts[e] + 255) >> 8;
      for (int i = 0; i < t; i++) { tileE[nt] = e; tileR[nt] = run + i * 256; nt++; }
      run += t << 8;
    }
    *nTiles = nt;
    float mean = 0.0f;
    for (int e = 0; e < NE; e++) mean += usage[e];
    mean *= (1.0f / NE);
    float var = 0.0f;
    for (int e = 0; e < NE; e++) { float d = usage[e] - mean; var += d * d; }
    var *= (1.0f / NE);
    float bal = sqrtf(var) / mean * 0.01f;
    float z = (zsum[0] / (float)N_TOK) * 0.001f;
    lossOut[0] = bal + z;
  }
}

// ---------------- scatter tokens into per-expert segments ----------------
__global__ void scatter_kernel(const int* __restrict__ idxb, const float* __restrict__ wbuf,
                               const int* __restrict__ poff, int* __restrict__ fill,
                               int* __restrict__ perm, float* __restrict__ permw,
                               int* __restrict__ pos) {
  __shared__ int lcnt[NE];
  __shared__ int lbase[NE];
  int t = threadIdx.x;
  if (t < NE) lcnt[t] = 0;
  __syncthreads();
  int i = blockIdx.x * 256 + t;          // grid sized exactly: i < NKTOT
  int e = idxb[i];
  int r = atomicAdd(&lcnt[e], 1);        // LDS rank within block
  __syncthreads();
  if (t < NE) lbase[t] = atomicAdd(&fill[t], lcnt[t]);
  __syncthreads();
  int p = poff[e] + lbase[e] + r;
  perm[p] = i >> 1;
  permw[p] = wbuf[i];
  pos[i] = p;
}

// ---------------- transpose+convert: src fp32 [R][C] -> dst bf16 [C][R], batched ----------------
__global__ void transpose_cvt_kernel(const float* __restrict__ src,
                                     unsigned short* __restrict__ dst, int R, int C) {
  __shared__ float tile[64][65];
  size_t bo = (size_t)blockIdx.z * R * C;
  src += bo; dst += bo;
  int r0 = blockIdx.x * 64, c0 = blockIdx.y * 64;
  int c = threadIdx.x & 63, r = threadIdx.x >> 6;
#pragma unroll
  for (int i = 0; i < 16; i++)
    tile[r + i * 4][c] = src[(size_t)(r0 + r + i * 4) * C + c0 + c];
  __syncthreads();
#pragma unroll
  for (int i = 0; i < 16; i++) {
    int oc = r + i * 4;           // src col -> dst row offset
    float v = tile[c][oc];        // = src[r0+c][c0+oc]
    dst[(size_t)(c0 + oc) * R + r0 + c] = f2bf(v);
  }
}

// ---------------- combine: out[t] += eout[pos0[t]] + eout[pos1[t]] ----------------
__global__ void combine_kernel(float* __restrict__ out,
                               const unsigned short* __restrict__ eout,
                               const int* __restrict__ pos) {
  int t = blockIdx.x;
  int d = threadIdx.x * 8;
  int p0 = pos[t * 2], p1 = pos[t * 2 + 1];
  float* o = out + (size_t)t * DM + d;
  const unsigned short* e0 = eout + (size_t)p0 * DM + d;
  const unsigned short* e1 = eout + (size_t)p1 * DM + d;
  float4 a = *(const float4*)(o);
  float4 b = *(const float4*)(o + 4);
  ushort4 u0a = *(const ushort4*)(e0), u0b = *(const ushort4*)(e0 + 4);
  ushort4 u1a = *(const ushort4*)(e1), u1b = *(const ushort4*)(e1 + 4);
  a.x += bf2f(u0a.x) + bf2f(u1a.x);
  a.y += bf2f(u0a.y) + bf2f(u1a.y);
  a.z += bf2f(u0a.z) + bf2f(u1a.z);
  a.w += bf2f(u0a.w) + bf2f(u1a.w);
  b.x += bf2f(u0b.x) + bf2f(u1b.x);
  b.y += bf2f(u0b.y) + bf2f(u1b.y);
  b.z += bf2f(u0b.z) + bf2f(u1b.z);
  b.w += bf2f(u0b.w) + bf2f(u1b.w);
  *(float4*)(o) = a;
  *(float4*)(o + 4) = b;
}

// ---------------- 256x256xBK64 bf16 MFMA GEMM, 8-wave 8-phase counted-vmcnt ----------------
// (kept for the N=4096 keys GEMMs; MODE 0 = shared keys, MODE 2 = expert keys)
template<int MODE>
__device__ __forceinline__ void gemm_body(
    const unsigned short* __restrict__ A,
    const unsigned short* __restrict__ BT,
    const float* __restrict__ bias,
    float* __restrict__ outF,
    unsigned short* __restrict__ outH,
    int Kd, int Nd,
    const int* __restrict__ perm,
    const float* __restrict__ permw,
    const int* __restrict__ tileE,
    const int* __restrict__ tileR,
    const int* __restrict__ nTiles) {
  __shared__ __align__(16) unsigned short As[2][16384];   // [slot][256*64]
  __shared__ __align__(16) unsigned short Bs[2][16384];

  int id = blockIdx.x;
  int xcd = id & 7, q = id >> 3;
  int mt, ntile;
  if (MODE == 0)      { mt = xcd * 4 + (q & 3); ntile = q >> 2; }   // 512 blk: 32m x 16n
  else                { mt = xcd * 9 + (q >> 4); ntile = q & 15; }  // 1152 blk: 72m x 16n

  int n0 = ntile * 256;
  int prow0 = 0, m0 = 0;
  if (MODE >= 2) {
    if (mt >= *nTiles) return;
    int e = tileE[mt];
    prow0 = tileR[mt];
    BT += (size_t)e * Kd * Nd;
    bias += (size_t)e * Nd;
  } else {
    m0 = mt * 256;
  }

  int t = threadIdx.x;
  int wid = t >> 6, lane = t & 63;
  int rsub = t >> 3;                // 0..63: row within a 64-row staging call
  int cc = (t & 7) ^ (rsub & 7);    // swizzled global 16B-chunk index
  const unsigned short* aptr[4];
  const unsigned short* bptr[4];
#pragma unroll
  for (int c = 0; c < 4; c++) {     // c = half*2 + sub; row r = c*64 + rsub
    int r = c * 64 + rsub;
    size_t grow;
    if (MODE == 2)      grow = (size_t)perm[prow0 + r];
    else                grow = (size_t)(m0 + r);
    aptr[c] = A + grow * Kd + cc * 8;
    bptr[c] = BT + (size_t)(n0 + r) * Kd + cc * 8;
  }
  // wave-uniform LDS staging bases (HW adds lane*16)
  char* aS = (char*)&As[0][0] + wid * 1024;
  char* bS = (char*)&Bs[0][0] + wid * 1024;

#define STAGE_A(kt, h, slot) do { \
    gload16(aptr[(h)*2]     + (kt)*64, aS + (slot)*32768 + (h)*16384); \
    gload16(aptr[(h)*2 + 1] + (kt)*64, aS + (slot)*32768 + (h)*16384 + 8192); } while (0)
#define STAGE_B(kt, h, slot) do { \
    gload16(bptr[(h)*2]     + (kt)*64, bS + (slot)*32768 + (h)*16384); \
    gload16(bptr[(h)*2 + 1] + (kt)*64, bS + (slot)*32768 + (h)*16384 + 8192); } while (0)

  int wr = wid >> 2, wc = wid & 3;          // wave tile: rows wr*128, cols wc*64
  int lr = lane & 15, lq = lane >> 4;
  int rx = lr & 7;
  int aoff = (wr * 128 + lr) * 64;          // element offsets within a slot
  int boff = (wc * 64 + lr) * 64;
  int c0 = (lq ^ rx) * 8;                   // kk=0 chunk; kk=1 is c0^32

  floatx4 acc[8][4];
#pragma unroll
  for (int i = 0; i < 8; i++)
#pragma unroll
    for (int j = 0; j < 4; j++) acc[i][j] = (floatx4){0.f, 0.f, 0.f, 0.f};

  int nkt = Kd >> 6;

  // prologue: tile0 all 4 halves + tile1 B-halves; wait tile0 landed.
  STAGE_A(0, 0, 0); STAGE_A(0, 1, 0);
  STAGE_B(0, 0, 0); STAGE_B(0, 1, 0);
  STAGE_B(1, 0, 1); STAGE_B(1, 1, 1);
  asm volatile("s_waitcnt vmcnt(4)" ::: "memory");
  SBAR;

  bhalf8 a[4][2], bL[2][2], bH[2][2];
  for (int kt = 0; kt < nkt; ++kt) {
    int s = kt & 1;
    const unsigned short* Ax = &As[0][0] + s * 16384;
    const unsigned short* Bx = &Bs[0][0] + s * 16384;

    // ---- phase 1: read A m-lo (8) + B n-lo (4); stage (kt+1).A0 ----
#pragma unroll
    for (int i = 0; i < 4; i++) {
      a[i][0] = *(const bhalf8*)&Ax[aoff + i * 1024 + c0];
      a[i][1] = *(const bhalf8*)&Ax[aoff + i * 1024 + (c0 ^ 32)];
    }
#pragma unroll
    for (int j = 0; j < 2; j++) {
      bL[j][0] = *(const bhalf8*)&Bx[boff + j * 1024 + c0];
      bL[j][1] = *(const bhalf8*)&Bx[boff + j * 1024 + (c0 ^ 32)];
    }
    if (kt + 1 < nkt) STAGE_A(kt + 1, 0, s ^ 1);
    SBAR;
    asm volatile("s_waitcnt lgkmcnt(0)" ::: "memory");
    __builtin_amdgcn_s_setprio(1);
#pragma unroll
    for (int kk = 0; kk < 2; kk++)
#pragma unroll
      for (int i = 0; i < 4; i++)
#pragma unroll
        for (int j = 0; j < 2; j++)
          acc[i][j] = __builtin_amdgcn_mfma_f32_16x16x32_bf16(a[i][kk], bL[j][kk], acc[i][j], 0, 0, 0);
    __builtin_amdgcn_s_setprio(0);
    SBAR;

    // ---- phase 2: read B n-hi (4); stage (kt+1).A1 ----
#pragma unroll
    for (int j = 0; j < 2; j++) {
      bH[j][0] = *(const bhalf8*)&Bx[boff + (j + 2) * 1024 + c0];
      bH[j][1] = *(const bhalf8*)&Bx[boff + (j + 2) * 1024 + (c0 ^ 32)];
    }
    if (kt + 1 < nkt) STAGE_A(kt + 1, 1, s ^ 1);
    SBAR;
    asm volatile("s_waitcnt lgkmcnt(0)" ::: "memory");
    __builtin_amdgcn_s_setprio(1);
#pragma unroll
    for (int kk = 0; kk < 2; kk++)
#pragma unroll
      for (int i = 0; i < 4; i++)
#pragma unroll
        for (int j = 0; j < 2; j++)
          acc[i][j + 2] = __builtin_amdgcn_mfma_f32_16x16x32_bf16(a[i][kk], bH[j][kk], acc[i][j + 2], 0, 0, 0);
    __builtin_amdgcn_s_setprio(0);
    SBAR;

    // ---- phase 3: read A m-hi (8, reuse regs); stage (kt+2).B0 into slot s ----
#pragma unroll
    for (int i = 0; i < 4; i++) {
      a[i][0] = *(const bhalf8*)&Ax[aoff + (i + 4) * 1024 + c0];
      a[i][1] = *(const bhalf8*)&Ax[aoff + (i + 4) * 1024 + (c0 ^ 32)];
    }
    if (kt + 2 < nkt) STAGE_B(kt + 2, 0, s);
    SBAR;
    asm volatile("s_waitcnt lgkmcnt(0)" ::: "memory");
    __builtin_amdgcn_s_setprio(1);
#pragma unroll
    for (int kk = 0; kk < 2; kk++)
#pragma unroll
      for (int i = 0; i < 4; i++)
#pragma unroll
        for (int j = 0; j < 2; j++)
          acc[i + 4][j] = __builtin_amdgcn_mfma_f32_16x16x32_bf16(a[i][kk], bL[j][kk], acc[i + 4][j], 0, 0, 0);
    __builtin_amdgcn_s_setprio(0);
    SBAR;

    // ---- phase 4: no reads; stage (kt+2).B1; counted vmcnt ----
    if (kt + 2 < nkt) {
      STAGE_B(kt + 2, 1, s);
      asm volatile("s_waitcnt vmcnt(4)" ::: "memory");   // leave only (kt+2).B0/B1
    } else {
      asm volatile("s_waitcnt vmcnt(0)" ::: "memory");   // tail: drain all
    }
    SBAR;
    __builtin_amdgcn_s_setprio(1);
#pragma unroll
    for (int kk = 0; kk < 2; kk++)
#pragma unroll
      for (int i = 0; i < 4; i++)
#pragma unroll
        for (int j = 0; j < 2; j++)
          acc[i + 4][j + 2] = __builtin_amdgcn_mfma_f32_16x16x32_bf16(a[i][kk], bH[j][kk], acc[i + 4][j + 2], 0, 0, 0);
    __builtin_amdgcn_s_setprio(0);
    SBAR;
  }
#undef STAGE_A
#undef STAGE_B

  // epilogue: frag D[row=lq*4+r][col=lr]
#pragma unroll
  for (int jj = 0; jj < 4; jj++) {
    int ncol = n0 + wc * 64 + jj * 16 + lr;
    float bb = bias[ncol];
#pragma unroll
    for (int i = 0; i < 8; i++) {
#pragma unroll
      for (int r = 0; r < 4; r++) {
        int mrow = wr * 128 + i * 16 + lq * 4 + r;      // local row 0..255
        float v = acc[i][jj][r] + bb;
        if (MODE == 0) {
          outH[(size_t)(m0 + mrow) * Nd + ncol] = f2bf(gelu_tanh(v));
        } else {
          outH[(size_t)(prow0 + mrow) * Nd + ncol] = f2bf(gelu_tanh(v));
        }
      }
    }
  }
}

// ---------------- 256x128xBK64 bf16 MFMA GEMM, 8-wave 2-phase, 3-slot ring ----------------
// 512 threads = 8 waves (4 M x 2 N of 64x64 wave tiles). LDS = 3 slots:
// A[3][256*64] + B[3][128*64] bf16 = 144 KB. While computing tile kt, tile kt+2
// is staged into slot (kt+2)%3 (= slot of kt-1, whose last reads completed >=2
// barriers earlier). vmcnt(6) at end of tile leaves exactly the newest tile's
// 6 loads in flight -> ~2 K-tiles of staging lead (covers L3 latency).
// MODE 1 = shared values (f32 out); MODE 3 = expert values (weighted bf16 out).
template<int MODE>
__device__ __forceinline__ void gemm_body128(
    const unsigned short* __restrict__ A,
    const unsigned short* __restrict__ BT,
    const float* __restrict__ bias,
    float* __restrict__ outF,
    unsigned short* __restrict__ outH,
    int Kd, int Nd,
    const float* __restrict__ permw,
    const int* __restrict__ tileE,
    const int* __restrict__ tileR,
    const int* __restrict__ nTiles) {
  __shared__ __align__(16) unsigned short As[3][16384];   // [slot][256*64]
  __shared__ __align__(16) unsigned short Bs[3][8192];    // [slot][128*64]

  int id = blockIdx.x;
  int xcd = id & 7, q = id >> 3;
  int mt, ntile;
  if (MODE == 1) { mt = xcd * 4 + (q & 3); ntile = q >> 2; }   // 256 blk: 32m x 8n
  else           { mt = xcd * 9 + (q >> 3); ntile = q & 7; }   // 576 blk: 72m x 8n

  int n0 = ntile * 128;
  int prow0 = 0, m0 = 0;
  if (MODE == 3) {
    if (mt >= *nTiles) return;
    prow0 = tileR[mt];
    int e = tileE[mt];
    BT += (size_t)e * Kd * Nd;
    bias += (size_t)e * Nd;
  } else {
    m0 = mt * 256;
  }

  int t = threadIdx.x;
  int wid = t >> 6, lane = t & 63;
  int rsub = t >> 3;                // 0..63: row within a 64-row staging call
  int cc = (t & 7) ^ (rsub & 7);    // swizzled global 16B-chunk index
  const unsigned short* aptr[4];    // A rows c*64+rsub, c=0..3
  const unsigned short* bptr[2];    // B rows c*64+rsub, c=0..1
#pragma unroll
  for (int c = 0; c < 4; c++) {
    int r = c * 64 + rsub;
    size_t grow = (MODE == 3) ? (size_t)(prow0 + r) : (size_t)(m0 + r);
    aptr[c] = A + grow * Kd + cc * 8;
  }
#pragma unroll
  for (int c = 0; c < 2; c++)
    bptr[c] = BT + (size_t)(n0 + c * 64 + rsub) * Kd + cc * 8;

  // wave-uniform LDS staging bases (HW adds lane*16)
  char* aS = (char*)&As[0][0] + wid * 1024;
  char* bS = (char*)&Bs[0][0] + wid * 1024;

  // per K-tile per wave: A = 4 gloads (2 halves x 2 calls), B = 2 gloads
#define STAGE_A128(kt, h, slot) do { \
    gload16(aptr[(h)*2]     + (kt)*64, aS + (slot)*32768 + (h)*16384); \
    gload16(aptr[(h)*2 + 1] + (kt)*64, aS + (slot)*32768 + (h)*16384 + 8192); } while (0)
#define STAGE_B128(kt, slot) do { \
    gload16(bptr[0] + (kt)*64, bS + (slot)*16384); \
    gload16(bptr[1] + (kt)*64, bS + (slot)*16384 + 8192); } while (0)

  int wr = wid >> 1, wc = wid & 1;          // wave tile: rows wr*64, cols wc*64
  int lr = lane & 15, lq = lane >> 4;
  int rx = lr & 7;
  int aoff = (wr * 64 + lr) * 64;           // element offsets within a slot
  int boff = (wc * 64 + lr) * 64;
  int c0 = (lq ^ rx) * 8;                   // kk=0 chunk; kk=1 is c0^32

  floatx4 acc[4][4];
#pragma unroll
  for (int i = 0; i < 4; i++)
#pragma unroll
    for (int j = 0; j < 4; j++) acc[i][j] = (floatx4){0.f, 0.f, 0.f, 0.f};

  int nkt = Kd >> 6;

  // prologue: stage tile0 -> slot0, tile1 -> slot1; wait tile0 landed (tile1's
  // 6 loads may still be in flight; they are drained by tile0's ph2 vmcnt(6)).
  STAGE_A128(0, 0, 0); STAGE_A128(0, 1, 0); STAGE_B128(0, 0);
  STAGE_A128(1, 0, 1); STAGE_A128(1, 1, 1); STAGE_B128(1, 1);
  asm volatile("s_waitcnt vmcnt(6)" ::: "memory");
  SBAR;

  bhalf8 a[4][2], bL[2][2], bH[2][2];
  int s = 0;
  for (int kt = 0; kt < nkt; ++kt) {
    int sn = s + 2; if (sn >= 3) sn -= 3;   // slot for tile kt+2 (= slot of kt-1)
    const unsigned short* Ax = &As[0][0] + s * 16384;
    const unsigned short* Bx = &Bs[0][0] + s * 8192;

    // ---- phase 1: read A all (8) + B j01 (4); stage (kt+2).A ----
#pragma unroll
    for (int i = 0; i < 4; i++) {
      a[i][0] = *(const bhalf8*)&Ax[aoff + i * 1024 + c0];
      a[i][1] = *(const bhalf8*)&Ax[aoff + i * 1024 + (c0 ^ 32)];
    }
#pragma unroll
    for (int j = 0; j < 2; j++) {
      bL[j][0] = *(const bhalf8*)&Bx[boff + j * 1024 + c0];
      bL[j][1] = *(const bhalf8*)&Bx[boff + j * 1024 + (c0 ^ 32)];
    }
    if (kt + 2 < nkt) { STAGE_A128(kt + 2, 0, sn); STAGE_A128(kt + 2, 1, sn); }
    SBAR;
    asm volatile("s_waitcnt lgkmcnt(0)" ::: "memory");
    __builtin_amdgcn_s_setprio(1);
#pragma unroll
    for (int kk = 0; kk < 2; kk++)
#pragma unroll
      for (int i = 0; i < 4; i++)
#pragma unroll
        for (int j = 0; j < 2; j++)
          acc[i][j] = __builtin_amdgcn_mfma_f32_16x16x32_bf16(a[i][kk], bL[j][kk], acc[i][j], 0, 0, 0);
    __builtin_amdgcn_s_setprio(0);
    SBAR;

    // ---- phase 2: read B j23 (4); stage (kt+2).B; counted vmcnt ----
#pragma unroll
    for (int j = 0; j < 2; j++) {
      bH[j][0] = *(const bhalf8*)&Bx[boff + (j + 2) * 1024 + c0];
      bH[j][1] = *(const bhalf8*)&Bx[boff + (j + 2) * 1024 + (c0 ^ 32)];
    }
    if (kt + 2 < nkt) {
      STAGE_B128(kt + 2, sn);
      asm volatile("s_waitcnt vmcnt(6)" ::: "memory");   // drain kt+1, keep kt+2
    } else {
      asm volatile("s_waitcnt vmcnt(0)" ::: "memory");   // tail: drain all
    }
    SBAR;
    asm volatile("s_waitcnt lgkmcnt(0)" ::: "memory");
    __builtin_amdgcn_s_setprio(1);
#pragma unroll
    for (int kk = 0; kk < 2; kk++)
#pragma unroll
      for (int i = 0; i < 4; i++)
#pragma unroll
        for (int j = 0; j < 2; j++)
          acc[i][j + 2] = __builtin_amdgcn_mfma_f32_16x16x32_bf16(a[i][kk], bH[j][kk], acc[i][j + 2], 0, 0, 0);
    __builtin_amdgcn_s_setprio(0);
    SBAR;

    s = s + 1; if (s >= 3) s = 0;
  }
#undef STAGE_A128
#undef STAGE_B128

  // epilogue: frag D[row=lq*4+r][col=lr]
#pragma unroll
  for (int jj = 0; jj < 4; jj++) {
    int ncol = n0 + wc * 64 + jj * 16 + lr;
    float bb = bias[ncol];
#pragma unroll
    for (int i = 0; i < 4; i++) {
#pragma unroll
      for (int r = 0; r < 4; r++) {
        int mrow = wr * 64 + i * 16 + lq * 4 + r;       // local row 0..255
        float v = acc[i][jj][r] + bb;
        if (MODE == 1) {
          outF[(size_t)(m0 + mrow) * Nd + ncol] = v;
        } else {
          int prow = prow0 + mrow;
          float w = permw[prow];
          outH[(size_t)prow * Nd + ncol] = f2bf(w * v);   // weighted expert out
        }
      }
    }
  }
}

// distinct names per mode so rocprof shows the per-GEMM breakdown
__global__ __launch_bounds__(512, 2) void gemm_shared_keys(
    const unsigned short* A, const unsigned short* BT, const float* bias,
    float* outF, unsigned short* outH, int Kd, int Nd,
    const int* perm, const float* permw, const int* tE, const int* tR, const int* nT) {
  gemm_body<0>(A, BT, bias, outF, outH, Kd, Nd, perm, permw, tE, tR, nT);
}
__global__ __launch_bounds__(512, 2) void gemm_expert_keys(
    const unsigned short* A, const unsigned short* BT, const float* bias,
    float* outF, unsigned short* outH, int Kd, int Nd,
    const int* perm, const float* permw, const int* tE, const int* tR, const int* nT) {
  gemm_body<2>(A, BT, bias, outF, outH, Kd, Nd, perm, permw, tE, tR, nT);
}
__global__ __launch_bounds__(512, 2) void gemm_shared_values(
    const unsigned short* A, const unsigned short* BT, const float* bias,
    float* outF, unsigned short* outH, int Kd, int Nd,
    const int* perm, const float* permw, const int* tE, const int* tR, const int* nT) {
  gemm_body128<1>(A, BT, bias, outF, outH, Kd, Nd, permw, tE, tR, nT);
}
__global__ __launch_bounds__(512, 2) void gemm_expert_values(
    const unsigned short* A, const unsigned short* BT, const float* bias,
    float* outF, unsigned short* outH, int Kd, int Nd,
    const int* perm, const float* permw, const int* tE, const int* tR, const int* nT) {
  gemm_body128<3>(A, BT, bias, outF, outH, Kd, Nd, permw, tE, tR, nT);
}

extern "C" void kernel_launch(void* const* d_in, const int* in_sizes, int n_in,
                              void* d_out, int out_size, void* d_ws, size_t ws_size,
                              hipStream_t stream) {
  const float* x        = (const float*)d_in[0];
  const float* gate_w   = (const float*)d_in[1];
  const float* keys_w   = (const float*)d_in[2];
  const float* keys_b   = (const float*)d_in[3];
  const float* values_w = (const float*)d_in[4];
  const float* values_b = (const float*)d_in[5];
  const float* sk_w     = (const float*)d_in[6];
  const float* sk_b     = (const float*)d_in[7];
  const float* sv_w     = (const float*)d_in[8];
  const float* sv_b     = (const float*)d_in[9];
  float* out = (float*)d_out;

  char* p = (char*)d_ws;
  unsigned short* xb   = (unsigned short*)p; p += (size_t)N_TOK * DM * 2;     // 16 MB
  unsigned short* wt   = (unsigned short*)p; p += (size_t)NE * DM * HD * 2;   // 64 MB (phased)
  unsigned short* hid  = (unsigned short*)p; p += (size_t)PERM_CAP * HD * 2;  // 151 MB
  unsigned short* eout = (unsigned short*)p; p += (size_t)PERM_CAP * DM * 2;  // 37.8 MB
  int*   idxb   = (int*)p;   p += NKTOT * 4;
  float* wbuf   = (float*)p; p += NKTOT * 4;
  int*   perm   = (int*)p;   p += PERM_CAP * 4;
  float* permw  = (float*)p; p += PERM_CAP * 4;
  int*   pos    = (int*)p;   p += NKTOT * 4;
  int*   counts = (int*)p;   p += NE * 4;
  int*   fill   = (int*)p;   p += NE * 4;
  int*   poff   = (int*)p;   p += NE * 4;
  float* usage  = (float*)p; p += NE * 4;
  float* zsum   = (float*)p; p += 16;
  int*   tileE  = (int*)p;   p += MAX_TILES * 4;
  int*   tileR  = (int*)p;   p += MAX_TILES * 4;
  int*   nTiles = (int*)p;   p += 16;

  float* lossOut = out + (size_t)N_TOK * DM;

  // 1) init + convert + router
  init_kernel<<<(PERM_CAP + 255) / 256, 256, 0, stream>>>(perm, permw, usage, zsum, counts, fill);
  cvt_x_kernel<<<(N_TOK * DM / 4 + 255) / 256, 256, 0, stream>>>(x, xb);
  router_kernel<<<N_TOK / RTOK_BLK, 256, 0, stream>>>(x, gate_w, idxb, wbuf, usage, zsum, counts);
  scan_kernel<<<1, 64, 0, stream>>>(counts, poff, tileE, tileR, nTiles, usage, zsum, lossOut);
  scatter_kernel<<<NKTOT / 256, 256, 0, stream>>>(idxb, wbuf, poff, fill, perm, permw, pos);

  // 2) shared expert: hid = gelu(x @ Wk + b); out = hid @ Wv + b
  transpose_cvt_kernel<<<dim3(DM / 64, HD / 64, 1), 256, 0, stream>>>(sk_w, wt, DM, HD);
  gemm_shared_keys<<<512, 512, 0, stream>>>(                // 8 xcd * 4 m * 16 n (2 waves exact)
      xb, wt, sk_b, nullptr, hid, DM, HD, perm, permw, tileE, tileR, nTiles);
  transpose_cvt_kernel<<<dim3(HD / 64, DM / 64, 1), 256, 0, stream>>>(sv_w, wt, HD, DM);
  gemm_shared_values<<<256, 512, 0, stream>>>(              // 8 xcd * 4 m * 8 n (1 wave exact)
      hid, wt, sv_b, out, nullptr, HD, DM, perm, permw, tileE, tileR, nTiles);

  // 3) routed experts (grouped, sparse top-2)
  transpose_cvt_kernel<<<dim3(DM / 64, HD / 64, NE), 256, 0, stream>>>(keys_w, wt, DM, HD);
  gemm_expert_keys<<<1152, 512, 0, stream>>>(               // 8 xcd * 9 m * 16 n
      xb, wt, keys_b, nullptr, hid, DM, HD, perm, permw, tileE, tileR, nTiles);
  transpose_cvt_kernel<<<dim3(HD / 64, DM / 64, NE), 256, 0, stream>>>(values_w, wt, HD, DM);
  gemm_expert_values<<<576, 512, 0, stream>>>(              // 8 xcd * 9 m * 8 n (T/2 blocks)
      hid, wt, values_b, nullptr, eout, HD, DM, perm, permw, tileE, tileR, nTiles);

  // 4) out += top-2 expert contributions
  combine_kernel<<<N_TOK, 128, 0, stream>>>(out, eout, pos);
}

// Round 4
// 926.387 us; speedup vs baseline: 1.2009x; 1.1002x over previous
//
#include <hip/hip_runtime.h>
#include <hip/hip_bf16.h>

// MoE top-2-of-8 FFN + shared expert + router losses, MI355X gfx950.
// R5: router/scatter atomic de-serialization (274us -> noise).
// R6/R7: 1-block/CU hand-phased GEMMs -> only ~570 TF steady (MfmaUtil 25%);
//     barrier/lgkm drains exposed chip-wide with no co-resident block to hide
//     them. R4's simple 128^2 dbuf body measured ~790 TF steady at 2 blocks/CU.
// R8: all four GEMMs on the m97-canonical structure: 128x128 tile, BK=64,
//     4 waves, SINGLE 32 KB LDS buffer, stage -> sync -> compute -> sync,
//     __launch_bounds__(256,4) -> 4 blocks/CU (VGPR ~88, LDS 32 KB). TLP from
//     4 co-resident blocks hides the per-block stage drain (m97/m114 thesis),
//     and smooths grid quantization (ev: 4.125 blocks/CU avg vs 2-deep 68%).

#define N_TOK 8192
#define DM    1024
#define HD    4096
#define NE    8
#define NKTOT 16384            // N_TOK * 2
#define PERM_CAP 17408         // NKTOT + NE*128 (segment padding)
#define MAX_TILES 136          // sum ceil(T_e/128) <= NKTOT/128 + NE
#define BAND 17                // MAX_TILES / 8 xcds
#define RTOK_BLK 16            // router tokens per block

typedef __attribute__((ext_vector_type(8))) short bhalf8;
typedef __attribute__((ext_vector_type(4))) float floatx4;

__device__ __forceinline__ unsigned short f2bf(float f) {
  union { float f; unsigned int u; } v; v.f = f;
  unsigned int u = v.u;
  return (unsigned short)((u + 0x7fffu + ((u >> 16) & 1u)) >> 16);  // RNE
}

__device__ __forceinline__ float bf2f(unsigned short h) {
  union { unsigned int u; float f; } v; v.u = ((unsigned int)h) << 16;
  return v.f;
}

__device__ __forceinline__ float gelu_tanh(float h) {
  // jax.nn.gelu default (approximate=True)
  float u = 0.7978845608028654f * (h + 0.044715f * h * h * h);
  float t = 1.0f - 2.0f / (1.0f + __expf(2.0f * u));   // tanh(u)
  return 0.5f * h * (1.0f + t);
}

// global -> LDS direct DMA, 16B/lane. LDS dest is wave-uniform base + lane*16.
__device__ __forceinline__ void gload16(const unsigned short* g, void* l) {
  __builtin_amdgcn_global_load_lds(
      (const __attribute__((address_space(1))) void*)g,
      (__attribute__((address_space(3))) void*)l, 16, 0, 0);
}

// ---------------- init (ws is poisoned 0xAA each call) ----------------
__global__ void init_kernel(int* perm, float* permw, float* usage, float* zsum,
                            int* counts, int* fill) {
  int i = blockIdx.x * 256 + threadIdx.x;
  if (i < PERM_CAP) { perm[i] = 0; permw[i] = 0.0f; }
  if (i < NE) { usage[i] = 0.0f; counts[i] = 0; fill[i] = 0; }
  if (i == 0) zsum[0] = 0.0f;
}

// ---------------- x fp32 -> bf16 ----------------
__global__ void cvt_x_kernel(const float* __restrict__ x, unsigned short* __restrict__ xb) {
  size_t i = (size_t)(blockIdx.x * 256 + threadIdx.x) * 4;
  float4 v = *(const float4*)(x + i);
  ushort4 o;
  o.x = f2bf(v.x); o.y = f2bf(v.y); o.z = f2bf(v.z); o.w = f2bf(v.w);
  *(ushort4*)(xb + i) = o;
}

// ---------------- router: logits, top-2 softmax, aux-loss partials ----------------
__global__ void router_kernel(const float* __restrict__ x, const float* __restrict__ gw,
                              int* __restrict__ idxb, float* __restrict__ wbuf,
                              float* __restrict__ usage, float* __restrict__ zsum,
                              int* __restrict__ counts) {
  __shared__ float s_use[NE];
  __shared__ int   s_cnt[NE];
  __shared__ float s_z;
  int t = threadIdx.x;
  if (t < NE) { s_use[t] = 0.0f; s_cnt[t] = 0; }
  if (t == 0) s_z = 0.0f;
  __syncthreads();

  int wave = t >> 6;
  int lane = t & 63;

  float luse[NE]; int lcnt[NE];
#pragma unroll
  for (int e = 0; e < NE; e++) { luse[e] = 0.0f; lcnt[e] = 0; }
  float lz = 0.0f;

#pragma unroll
  for (int i = 0; i < 4; i++) {
    int n = blockIdx.x * RTOK_BLK + wave * 4 + i;
    const float* xr = x + (size_t)n * DM;
    float acc[NE];
#pragma unroll
    for (int e = 0; e < NE; e++) acc[e] = 0.0f;
    for (int d = lane; d < DM; d += 64) {
      float xv = xr[d];
      const float* g = gw + (size_t)d * NE;
#pragma unroll
      for (int e = 0; e < NE; e++) acc[e] += xv * g[e];
    }
#pragma unroll
    for (int e = 0; e < NE; e++) {
#pragma unroll
      for (int off = 32; off > 0; off >>= 1) acc[e] += __shfl_xor(acc[e], off);
    }
    if (lane == 0) {
      float m1 = acc[0]; int i1 = 0;
#pragma unroll
      for (int e = 1; e < NE; e++) if (acc[e] > m1) { m1 = acc[e]; i1 = e; }
      float m2 = -3.0e38f; int i2 = 0;
#pragma unroll
      for (int e = 0; e < NE; e++) if (e != i1 && acc[e] > m2) { m2 = acc[e]; i2 = e; }
      float e1 = __expf(m2 - m1);
      float w1 = 1.0f / (1.0f + e1);
      float w2 = e1 / (1.0f + e1);
      float s = 0.0f;
#pragma unroll
      for (int e = 0; e < NE; e++) s += __expf(acc[e] - m1);
      float lse = m1 + __logf(s);
      idxb[n * 2 + 0] = i1; idxb[n * 2 + 1] = i2;
      wbuf[n * 2 + 0] = w1; wbuf[n * 2 + 1] = w2;
      luse[i1] += w1; luse[i2] += w2;
      lcnt[i1]++;     lcnt[i2]++;
      lz += lse * lse;
    }
  }

  if (lane == 0) {
#pragma unroll
    for (int e = 0; e < NE; e++) {
      atomicAdd(&s_use[e], luse[e]);
      atomicAdd(&s_cnt[e], lcnt[e]);
    }
    atomicAdd(&s_z, lz);
  }
  __syncthreads();
  if (t < NE) {
    atomicAdd(&usage[t], s_use[t]);
    atomicAdd(&counts[t], s_cnt[t]);
  }
  if (t == 0) atomicAdd(zsum, s_z);
}

// ---------------- scan: padded segment offsets, tile table, router loss ----------------
__global__ void scan_kernel(const int* __restrict__ counts, int* __restrict__ poff,
                            int* __restrict__ tileE, int* __restrict__ tileR,
                            int* __restrict__ nTiles,
                            const float* __restrict__ usage, const float* __restrict__ zsum,
                            float* __restrict__ lossOut) {
  if (threadIdx.x == 0 && blockIdx.x == 0) {
    int run = 0, nt = 0;
    for (int e = 0; e < NE; e++) {
      poff[e] = run;
      int t = (counts[e] + 127) >> 7;
      for (int i = 0; i < t; i++) { tileE[nt] = e; tileR[nt] = run + i * 128; nt++; }
      run += t << 7;
    }
    *nTiles = nt;
    float mean = 0.0f;
    for (int e = 0; e < NE; e++) mean += usage[e];
    mean *= (1.0f / NE);
    float var = 0.0f;
    for (int e = 0; e < NE; e++) { float d = usage[e] - mean; var += d * d; }
    var *= (1.0f / NE);
    float bal = sqrtf(var) / mean * 0.01f;
    float z = (zsum[0] / (float)N_TOK) * 0.001f;
    lossOut[0] = bal + z;
  }
}

// ---------------- scatter tokens into per-expert segments ----------------
__global__ void scatter_kernel(const int* __restrict__ idxb, const float* __restrict__ wbuf,
                               const int* __restrict__ poff, int* __restrict__ fill,
                               int* __restrict__ perm, float* __restrict__ permw,
                               int* __restrict__ pos) {
  __shared__ int lcnt[NE];
  __shared__ int lbase[NE];
  int t = threadIdx.x;
  if (t < NE) lcnt[t] = 0;
  __syncthreads();
  int i = blockIdx.x * 256 + t;          // grid sized exactly: i < NKTOT
  int e = idxb[i];
  int r = atomicAdd(&lcnt[e], 1);        // LDS rank within block
  __syncthreads();
  if (t < NE) lbase[t] = atomicAdd(&fill[t], lcnt[t]);
  __syncthreads();
  int p = poff[e] + lbase[e] + r;
  perm[p] = i >> 1;
  permw[p] = wbuf[i];
  pos[i] = p;
}

// ---------------- transpose+convert: src fp32 [R][C] -> dst bf16 [C][R], batched ----------------
__global__ void transpose_cvt_kernel(const float* __restrict__ src,
                                     unsigned short* __restrict__ dst, int R, int C) {
  __shared__ float tile[64][65];
  size_t bo = (size_t)blockIdx.z * R * C;
  src += bo; dst += bo;
  int r0 = blockIdx.x * 64, c0 = blockIdx.y * 64;
  int c = threadIdx.x & 63, r = threadIdx.x >> 6;
#pragma unroll
  for (int i = 0; i < 16; i++)
    tile[r + i * 4][c] = src[(size_t)(r0 + r + i * 4) * C + c0 + c];
  __syncthreads();
#pragma unroll
  for (int i = 0; i < 16; i++) {
    int oc = r + i * 4;           // src col -> dst row offset
    float v = tile[c][oc];        // = src[r0+c][c0+oc]
    dst[(size_t)(c0 + oc) * R + r0 + c] = f2bf(v);
  }
}

// ---------------- combine: out[t] += eout[pos0[t]] + eout[pos1[t]] ----------------
__global__ void combine_kernel(float* __restrict__ out,
                               const unsigned short* __restrict__ eout,
                               const int* __restrict__ pos) {
  int t = blockIdx.x;
  int d = threadIdx.x * 8;
  int p0 = pos[t * 2], p1 = pos[t * 2 + 1];
  float* o = out + (size_t)t * DM + d;
  const unsigned short* e0 = eout + (size_t)p0 * DM + d;
  const unsigned short* e1 = eout + (size_t)p1 * DM + d;
  float4 a = *(const float4*)(o);
  float4 b = *(const float4*)(o + 4);
  ushort4 u0a = *(const ushort4*)(e0), u0b = *(const ushort4*)(e0 + 4);
  ushort4 u1a = *(const ushort4*)(e1), u1b = *(const ushort4*)(e1 + 4);
  a.x += bf2f(u0a.x) + bf2f(u1a.x);
  a.y += bf2f(u0a.y) + bf2f(u1a.y);
  a.z += bf2f(u0a.z) + bf2f(u1a.z);
  a.w += bf2f(u0a.w) + bf2f(u1a.w);
  b.x += bf2f(u0b.x) + bf2f(u1b.x);
  b.y += bf2f(u0b.y) + bf2f(u1b.y);
  b.z += bf2f(u0b.z) + bf2f(u1b.z);
  b.w += bf2f(u0b.w) + bf2f(u1b.w);
  *(float4*)(o) = a;
  *(float4*)(o + 4) = b;
}

// ---------------- 128x128xBK64 bf16 MFMA GEMM, m97-canonical single buffer ----------------
// 256 threads = 4 waves (2x2 of 64x64 wave tiles). LDS: A[128][64]+B[128][64]
// bf16 = 32 KB -> 4 blocks/CU at __launch_bounds__(256,4). Per K-step:
// stage (8 x global_load_lds dwordx4) -> __syncthreads (drains vmcnt) ->
// 2x 16x16x32 k-steps of 4x4 MFMA -> __syncthreads. Stage drain is hidden by
// the 3 co-resident sibling blocks (inter-block TLP), not intra-block dbuf.
// Staging: pre-swizzled global chunk (gc = (t&7)^(rsub&7)) + linear LDS dest;
// read side XORs chunk with row&7 -> bank-conflict free (verified 0).
template<int MODE>
__device__ __forceinline__ void gemm_body(
    const unsigned short* __restrict__ A,
    const unsigned short* __restrict__ BT,
    const float* __restrict__ bias,
    float* __restrict__ outF,
    unsigned short* __restrict__ outH,
    int Kd, int Nd,
    const int* __restrict__ perm,
    const float* __restrict__ permw,
    const int* __restrict__ tileE,
    const int* __restrict__ tileR,
    const int* __restrict__ nTiles) {
  __shared__ __align__(16) unsigned short As[128 * 64];
  __shared__ __align__(16) unsigned short Bs[128 * 64];

  int id = blockIdx.x;
  int xcd = id & 7, q = id >> 3;
  int mt, ntile;
  if (MODE == 0) {              // band 8m, m-fastest: pin A-band + B-slab in L2
    mt = xcd * 8 + (q & 7);
    ntile = q >> 3;
  } else if (MODE == 1) {       // band 8m, n-fastest
    ntile = q & 7;
    mt = xcd * 8 + (q >> 3);
  } else if (MODE == 2) {       // band 17m, supertile 4m x 8n
    int n_in = q & 7, m_in = (q >> 3) & 3, ng = (q >> 5) & 3, mg = q >> 7;
    int mband = mg * 4 + m_in;
    if (mband >= BAND) return;
    mt = xcd * BAND + mband;
    ntile = ng * 8 + n_in;
  } else {                      // band 17m, n-fastest per m
    mt = xcd * BAND + (q >> 3);
    ntile = q & 7;
  }

  int n0 = ntile * 128;
  int prow0 = 0, m0 = 0;
  if (MODE >= 2) {
    if (mt >= *nTiles) return;
    int e = tileE[mt];
    prow0 = tileR[mt];
    BT += (size_t)e * Kd * Nd;
    bias += (size_t)e * Nd;
  } else {
    m0 = mt * 128;
  }

  int t = threadIdx.x;
  int rsub = t >> 3;               // 0..31: row within 32-row staging slab
  int gc = (t & 7) ^ (rsub & 7);   // swizzled global 16B-chunk index
  const unsigned short* aptr[4];
  const unsigned short* bptr[4];
#pragma unroll
  for (int p = 0; p < 4; p++) {
    int r = rsub + p * 32;
    size_t grow;
    if (MODE == 2)      grow = (size_t)perm[prow0 + r];
    else if (MODE == 3) grow = (size_t)(prow0 + r);
    else                grow = (size_t)(m0 + r);
    aptr[p] = A + grow * Kd + gc * 8;
    bptr[p] = BT + (size_t)(n0 + r) * Kd + gc * 8;
  }
  // wave-uniform LDS staging bases (lane*16 is added by HW)
  char* ldsA = (char*)As + (t & 192) * 16;
  char* ldsB = (char*)Bs + (t & 192) * 16;

  int lane = t & 63;
  int wv = t >> 6;
  int wm = (wv >> 1) * 64, wn = (wv & 1) * 64;
  int lr = lane & 15, lq = lane >> 4;
  int rx = lr & 7;                  // read-side row XOR key

  floatx4 acc[4][4];
#pragma unroll
  for (int i = 0; i < 4; i++)
#pragma unroll
    for (int j = 0; j < 4; j++) acc[i][j] = (floatx4){0.f, 0.f, 0.f, 0.f};

  for (int k0 = 0; k0 < Kd; k0 += 64) {
#pragma unroll
    for (int p = 0; p < 4; p++) {
      gload16(aptr[p] + k0, ldsA + p * 4096);
      gload16(bptr[p] + k0, ldsB + p * 4096);
    }
    __syncthreads();               // drains vmcnt(0): tile staged
#pragma unroll
    for (int kk = 0; kk < 2; kk++) {       // two 16x16x32 k-steps
      int ca = kk * 4 + lq;                // global chunk for this frag
      bhalf8 af[4], bf[4];
#pragma unroll
      for (int i = 0; i < 4; i++) {
        af[i] = *(const bhalf8*)&As[(wm + i * 16 + lr) * 64 + ((ca ^ rx) * 8)];
        bf[i] = *(const bhalf8*)&Bs[(wn + i * 16 + lr) * 64 + ((ca ^ rx) * 8)];
      }
#pragma unroll
      for (int mtile = 0; mtile < 4; mtile++)
#pragma unroll
        for (int ntl = 0; ntl < 4; ntl++)
          acc[mtile][ntl] = __builtin_amdgcn_mfma_f32_16x16x32_bf16(af[mtile], bf[ntl], acc[mtile][ntl], 0, 0, 0);
    }
    __syncthreads();               // protect buffer before next stage
  }

  // epilogue: D[row=(lane>>4)*4+reg][col=lane&15]
#pragma unroll
  for (int mtile = 0; mtile < 4; mtile++) {
#pragma unroll
    for (int ntl = 0; ntl < 4; ntl++) {
      int ncol = n0 + wn + ntl * 16 + lr;
      float bb = bias[ncol];
#pragma unroll
      for (int r = 0; r < 4; r++) {
        int mrow = wm + mtile * 16 + lq * 4 + r;    // local row 0..127
        float v = acc[mtile][ntl][r] + bb;
        if (MODE == 0) {
          outH[(size_t)(m0 + mrow) * Nd + ncol] = f2bf(gelu_tanh(v));
        } else if (MODE == 1) {
          outF[(size_t)(m0 + mrow) * Nd + ncol] = v;
        } else if (MODE == 2) {
          outH[(size_t)(prow0 + mrow) * Nd + ncol] = f2bf(gelu_tanh(v));
        } else {
          int prow = prow0 + mrow;
          float w = permw[prow];
          outH[(size_t)prow * Nd + ncol] = f2bf(w * v);   // weighted expert out
        }
      }
    }
  }
}

// distinct names per mode so rocprof shows the per-GEMM breakdown
__global__ __launch_bounds__(256, 4) void gemm_shared_keys(
    const unsigned short* A, const unsigned short* BT, const float* bias,
    float* outF, unsigned short* outH, int Kd, int Nd,
    const int* perm, const float* permw, const int* tE, const int* tR, const int* nT) {
  gemm_body<0>(A, BT, bias, outF, outH, Kd, Nd, perm, permw, tE, tR, nT);
}
__global__ __launch_bounds__(256, 4) void gemm_shared_values(
    const unsigned short* A, const unsigned short* BT, const float* bias,
    float* outF, unsigned short* outH, int Kd, int Nd,
    const int* perm, const float* permw, const int* tE, const int* tR, const int* nT) {
  gemm_body<1>(A, BT, bias, outF, outH, Kd, Nd, perm, permw, tE, tR, nT);
}
__global__ __launch_bounds__(256, 4) void gemm_expert_keys(
    const unsigned short* A, const unsigned short* BT, const float* bias,
    float* outF, unsigned short* outH, int Kd, int Nd,
    const int* perm, const float* permw, const int* tE, const int* tR, const int* nT) {
  gemm_body<2>(A, BT, bias, outF, outH, Kd, Nd, perm, permw, tE, tR, nT);
}
__global__ __launch_bounds__(256, 4) void gemm_expert_values(
    const unsigned short* A, const unsigned short* BT, const float* bias,
    float* outF, unsigned short* outH, int Kd, int Nd,
    const int* perm, const float* permw, const int* tE, const int* tR, const int* nT) {
  gemm_body<3>(A, BT, bias, outF, outH, Kd, Nd, perm, permw, tE, tR, nT);
}

extern "C" void kernel_launch(void* const* d_in, const int* in_sizes, int n_in,
                              void* d_out, int out_size, void* d_ws, size_t ws_size,
                              hipStream_t stream) {
  const float* x        = (const float*)d_in[0];
  const float* gate_w   = (const float*)d_in[1];
  const float* keys_w   = (const float*)d_in[2];
  const float* keys_b   = (const float*)d_in[3];
  const float* values_w = (const float*)d_in[4];
  const float* values_b = (const float*)d_in[5];
  const float* sk_w     = (const float*)d_in[6];
  const float* sk_b     = (const float*)d_in[7];
  const float* sv_w     = (const float*)d_in[8];
  const float* sv_b     = (const float*)d_in[9];
  float* out = (float*)d_out;

  char* p = (char*)d_ws;
  unsigned short* xb   = (unsigned short*)p; p += (size_t)N_TOK * DM * 2;     // 16 MB
  unsigned short* wt   = (unsigned short*)p; p += (size_t)NE * DM * HD * 2;   // 64 MB (phased)
  unsigned short* hid  = (unsigned short*)p; p += (size_t)PERM_CAP * HD * 2;  // 142.6 MB
  unsigned short* eout = (unsigned short*)p; p += (size_t)PERM_CAP * DM * 2;  // 35.7 MB
  int*   idxb   = (int*)p;   p += NKTOT * 4;
  float* wbuf   = (float*)p; p += NKTOT * 4;
  int*   perm   = (int*)p;   p += PERM_CAP * 4;
  float* permw  = (float*)p; p += PERM_CAP * 4;
  int*   pos    = (int*)p;   p += NKTOT * 4;
  int*   counts = (int*)p;   p += NE * 4;
  int*   fill   = (int*)p;   p += NE * 4;
  int*   poff   = (int*)p;   p += NE * 4;
  float* usage  = (float*)p; p += NE * 4;
  float* zsum   = (float*)p; p += 16;
  int*   tileE  = (int*)p;   p += MAX_TILES * 4;
  int*   tileR  = (int*)p;   p += MAX_TILES * 4;
  int*   nTiles = (int*)p;   p += 16;

  float* lossOut = out + (size_t)N_TOK * DM;

  // 1) init + convert + router
  init_kernel<<<(PERM_CAP + 255) / 256, 256, 0, stream>>>(perm, permw, usage, zsum, counts, fill);
  cvt_x_kernel<<<(N_TOK * DM / 4 + 255) / 256, 256, 0, stream>>>(x, xb);
  router_kernel<<<N_TOK / RTOK_BLK, 256, 0, stream>>>(x, gate_w, idxb, wbuf, usage, zsum, counts);
  scan_kernel<<<1, 64, 0, stream>>>(counts, poff, tileE, tileR, nTiles, usage, zsum, lossOut);
  scatter_kernel<<<NKTOT / 256, 256, 0, stream>>>(idxb, wbuf, poff, fill, perm, permw, pos);

  // 2) shared expert: hid = gelu(x @ Wk + b); out = hid @ Wv + b
  transpose_cvt_kernel<<<dim3(DM / 64, HD / 64, 1), 256, 0, stream>>>(sk_w, wt, DM, HD);
  gemm_shared_keys<<<2048, 256, 0, stream>>>(             // 8 xcd * 8 m * 32 n (8/CU exact)
      xb, wt, sk_b, nullptr, hid, DM, HD, perm, permw, tileE, tileR, nTiles);
  transpose_cvt_kernel<<<dim3(HD / 64, DM / 64, 1), 256, 0, stream>>>(sv_w, wt, HD, DM);
  gemm_shared_values<<<512, 256, 0, stream>>>(            // 8 xcd * 8 m * 8 n
      hid, wt, sv_b, out, nullptr, HD, DM, perm, permw, tileE, tileR, nTiles);

  // 3) routed experts (grouped, sparse top-2)
  transpose_cvt_kernel<<<dim3(DM / 64, HD / 64, NE), 256, 0, stream>>>(keys_w, wt, DM, HD);
  gemm_expert_keys<<<5120, 256, 0, stream>>>(             // 8 xcd * 20(m pad) * 32 n
      xb, wt, keys_b, nullptr, hid, DM, HD, perm, permw, tileE, tileR, nTiles);
  transpose_cvt_kernel<<<dim3(HD / 64, DM / 64, NE), 256, 0, stream>>>(values_w, wt, HD, DM);
  gemm_expert_values<<<1088, 256, 0, stream>>>(           // 8 xcd * 17 m * 8 n
      hid, wt, values_b, nullptr, eout, HD, DM, perm, permw, tileE, tileR, nTiles);

  // 4) out += top-2 expert contributions
  combine_kernel<<<N_TOK, 128, 0, stream>>>(out, eout, pos);
}